// Round 2
// baseline (915.856 us; speedup 1.0000x reference)
//
#include <hip/hip_runtime.h>
#include <math.h>

#define D 256
#define BGRAPH 1024
#define H 8
#define NW 4
#define CDIM 2304   // 2048 attn cols + 256 mean-residual cols

static constexpr float EPS = 1e-5f;
static constexpr float MEAN_RES_SCALE = 0.2f;
static constexpr float INV_SQRT_HD = 0.17677669529663687f; // 1/sqrt(32)

// ---------------------------------------------------------------- offsets
__global__ void k_offsets(const int* __restrict__ batch, int* __restrict__ offs, int N) {
    int n = blockIdx.x * blockDim.x + threadIdx.x;
    if (n >= N) return;
    int bn = batch[n];
    if (bn < 0) bn = 0;
    if (bn >= BGRAPH) bn = BGRAPH - 1;
    if (n == 0) {
        offs[BGRAPH] = N;
        for (int bb = 0; bb <= bn; ++bb) offs[bb] = 0;
    } else {
        int bp = batch[n - 1];
        if (bp < 0) bp = 0;
        if (bp >= BGRAPH) bp = BGRAPH - 1;
        if (bp != bn)
            for (int bb = bp + 1; bb <= bn; ++bb) offs[bb] = n;
    }
    if (n == N - 1)
        for (int bb = bn + 1; bb < BGRAPH; ++bb) offs[bb] = N;
}

// ------------------------------------- pool (mean/max) + q LN + Wkq, fused
__global__ __launch_bounds__(256) void k_pool(
    const float4* __restrict__ h4, const int* __restrict__ offs,
    const float* __restrict__ Wq, const float* __restrict__ lnq_w,
    const float* __restrict__ lnq_b, const float* __restrict__ Wk,
    const float* __restrict__ logit_scale,
    float* __restrict__ Wkq_g, float* __restrict__ App) {
    __shared__ alignas(16) float psum[NW][D];
    __shared__ alignas(16) float pmax[NW][D];
    __shared__ alignas(16) float cat_s[2 * D];
    __shared__ alignas(16) float q_s[D];
    __shared__ float red_s[2 * NW];

    int b = blockIdx.x;
    int t = threadIdx.x;
    int l = t & 63, w = t >> 6;
    int s = offs[b], e = offs[b + 1];
    int cnt = e - s;

    float4 sum4 = {0.f, 0.f, 0.f, 0.f};
    float4 max4 = {-INFINITY, -INFINITY, -INFINITY, -INFINITY};
    for (int n = s + w; n < e; n += NW) {
        float4 x = h4[(size_t)n * 64 + l];
        sum4.x += x.x; sum4.y += x.y; sum4.z += x.z; sum4.w += x.w;
        max4.x = fmaxf(max4.x, x.x); max4.y = fmaxf(max4.y, x.y);
        max4.z = fmaxf(max4.z, x.z); max4.w = fmaxf(max4.w, x.w);
    }
    *(float4*)&psum[w][4 * l] = sum4;
    *(float4*)&pmax[w][4 * l] = max4;
    __syncthreads();

    int d = t;
    float ssum = psum[0][d] + psum[1][d] + psum[2][d] + psum[3][d];
    float smax = fmaxf(fmaxf(pmax[0][d], pmax[1][d]), fmaxf(pmax[2][d], pmax[3][d]));
    float mean = ssum / (cnt > 0 ? (float)cnt : 1.f);
    if (cnt == 0) { mean = 0.f; smax = 0.f; }
    cat_s[d] = mean;
    cat_s[D + d] = smax;
    App[(size_t)b * CDIM + 2048 + d] = MEAN_RES_SCALE * mean;
    __syncthreads();

    // q_pre[d] = cat . Wq[d, :]
    float qp = 0.f;
    const float4* wq4 = (const float4*)(Wq + (size_t)d * 2 * D);
    #pragma unroll 4
    for (int jj = 0; jj < 128; ++jj) {
        float4 wv = wq4[jj];
        float4 cv = *(const float4*)&cat_s[4 * jj];
        qp += wv.x * cv.x + wv.y * cv.y + wv.z * cv.z + wv.w * cv.w;
    }
    // LayerNorm over the 256 q_pre values (one per thread)
    float v1 = qp, v2 = qp * qp;
    #pragma unroll
    for (int dd = 1; dd < 64; dd <<= 1) {
        v1 += __shfl_xor(v1, dd);
        v2 += __shfl_xor(v2, dd);
    }
    if (l == 0) { red_s[w] = v1; red_s[NW + w] = v2; }
    __syncthreads();
    float S1 = red_s[0] + red_s[1] + red_s[2] + red_s[3];
    float S2 = red_s[4] + red_s[5] + red_s[6] + red_s[7];
    float mu = S1 * (1.f / D);
    float var = S2 * (1.f / D) - mu * mu;
    float rstd = rsqrtf(var + EPS);
    q_s[d] = (qp - mu) * rstd * lnq_w[d] + lnq_b[d];
    __syncthreads();

    // Wkq[b,hh,j] = scale * sum_r q[hh*32+r] * Wk[hh*32+r, j]   (j = t)
    float scale = logit_scale[0] * INV_SQRT_HD;
    int j = t;
    #pragma unroll
    for (int hh = 0; hh < H; ++hh) {
        float acc = 0.f;
        #pragma unroll 8
        for (int r = 0; r < 32; ++r)
            acc += q_s[hh * 32 + r] * Wk[(size_t)(hh * 32 + r) * D + j];
        Wkq_g[(size_t)b * 2048 + hh * D + j] = acc * scale;
    }
}

// --------------------------- per-graph LN + logits + online softmax + A acc
__global__ __launch_bounds__(256) void k_attn(
    const float4* __restrict__ h4, const int* __restrict__ offs,
    const float* __restrict__ lnkv_w, const float* __restrict__ lnkv_b,
    const int* __restrict__ cdr_mask, const int* __restrict__ iface_mask,
    const float* __restrict__ cdr_bias, const float* __restrict__ iface_bias,
    const float* __restrict__ Wkq_g, float* __restrict__ App) {
    __shared__ alignas(16) float wkq_s[H * D];
    __shared__ alignas(16) float wv_s[D];
    __shared__ alignas(16) float bv_s[D];
    __shared__ float mz_s[NW][H];
    __shared__ float zz_s[NW][H];
    __shared__ alignas(16) float Amrg[NW - 1][H * D];

    int b = blockIdx.x;
    int t = threadIdx.x;
    int l = t & 63, w = t >> 6;
    for (int i = t; i < H * D; i += 256) wkq_s[i] = Wkq_g[(size_t)b * 2048 + i];
    wv_s[t] = lnkv_w[t];
    bv_s[t] = lnkv_b[t];
    int s = offs[b], e = offs[b + 1];
    float cb = cdr_bias[0], ib = iface_bias[0];
    __syncthreads();

    if (s == e) {  // empty graph (shouldn't occur, but keep App defined)
        for (int i = t; i < H * D; i += 256) App[(size_t)b * CDIM + i] = 0.f;
        return;
    }

    // hoisted invariants (per lane)
    float4 w4 = *(const float4*)&wv_s[4 * l];
    float4 b4 = *(const float4*)&bv_s[4 * l];
    float4 wq4[H];
    #pragma unroll
    for (int hh = 0; hh < H; ++hh) wq4[hh] = *(const float4*)&wkq_s[hh * D + 4 * l];

    float m[H], z[H];
    float4 A4[H];
    #pragma unroll
    for (int hh = 0; hh < H; ++hh) {
        m[hh] = -INFINITY; z[hh] = 0.f;
        A4[hh].x = 0.f; A4[hh].y = 0.f; A4[hh].z = 0.f; A4[hh].w = 0.f;
    }

    for (int n = s + w; n < e; n += NW) {
        float4 x = h4[(size_t)n * 64 + l];
        float s1 = x.x + x.y + x.z + x.w;
        float s2 = x.x * x.x + x.y * x.y + x.z * x.z + x.w * x.w;
        #pragma unroll
        for (int dd = 1; dd < 64; dd <<= 1) {
            s1 += __shfl_xor(s1, dd);
            s2 += __shfl_xor(s2, dd);
        }
        float mu = s1 * (1.f / D);
        float var = s2 * (1.f / D) - mu * mu;
        float a = rsqrtf(var + EPS);
        float c = -mu * a;
        float4 hl;
        hl.x = fmaf(fmaf(x.x, a, c), w4.x, b4.x);
        hl.y = fmaf(fmaf(x.y, a, c), w4.y, b4.y);
        hl.z = fmaf(fmaf(x.z, a, c), w4.z, b4.z);
        hl.w = fmaf(fmaf(x.w, a, c), w4.w, b4.w);

        float p[H];
        #pragma unroll
        for (int hh = 0; hh < H; ++hh) {
            float4 wq = wq4[hh];
            p[hh] = hl.x * wq.x + hl.y * wq.y + hl.z * wq.z + hl.w * wq.w;
        }
        #pragma unroll
        for (int dd = 1; dd < 64; dd <<= 1) {
            #pragma unroll
            for (int hh = 0; hh < H; ++hh) p[hh] += __shfl_xor(p[hh], dd);
        }
        float bias = cb * (float)cdr_mask[n] + ib * (float)iface_mask[n];
        float nm[H];
        bool upd = false;
        #pragma unroll
        for (int hh = 0; hh < H; ++hh) {
            p[hh] += bias;
            nm[hh] = fmaxf(m[hh], p[hh]);
            upd = upd || (nm[hh] > m[hh]);
        }
        if (upd) {
            #pragma unroll
            for (int hh = 0; hh < H; ++hh) {
                float sc = __expf(m[hh] - nm[hh]);   // exp(-inf)=0 on first hit
                float ev = __expf(p[hh] - nm[hh]);
                z[hh] = z[hh] * sc + ev;
                A4[hh].x = fmaf(A4[hh].x, sc, ev * hl.x);
                A4[hh].y = fmaf(A4[hh].y, sc, ev * hl.y);
                A4[hh].z = fmaf(A4[hh].z, sc, ev * hl.z);
                A4[hh].w = fmaf(A4[hh].w, sc, ev * hl.w);
                m[hh] = nm[hh];
            }
        } else {
            #pragma unroll
            for (int hh = 0; hh < H; ++hh) {
                float ev = __expf(p[hh] - m[hh]);
                z[hh] += ev;
                A4[hh].x = fmaf(ev, hl.x, A4[hh].x);
                A4[hh].y = fmaf(ev, hl.y, A4[hh].y);
                A4[hh].z = fmaf(ev, hl.z, A4[hh].z);
                A4[hh].w = fmaf(ev, hl.w, A4[hh].w);
            }
        }
    }

    // merge 4 waves
    if (l == 0) {
        #pragma unroll
        for (int hh = 0; hh < H; ++hh) { mz_s[w][hh] = m[hh]; zz_s[w][hh] = z[hh]; }
    }
    __syncthreads();
    float fw[H], zst[H];
    #pragma unroll
    for (int hh = 0; hh < H; ++hh) {
        float ms = fmaxf(fmaxf(mz_s[0][hh], mz_s[1][hh]), fmaxf(mz_s[2][hh], mz_s[3][hh]));
        float zs = 0.f;
        #pragma unroll
        for (int ww = 0; ww < NW; ++ww) zs += zz_s[ww][hh] * __expf(mz_s[ww][hh] - ms);
        zst[hh] = zs;
        fw[hh] = __expf(m[hh] - ms);
    }
    if (w > 0) {
        #pragma unroll
        for (int hh = 0; hh < H; ++hh) {
            float4 r;
            r.x = A4[hh].x * fw[hh]; r.y = A4[hh].y * fw[hh];
            r.z = A4[hh].z * fw[hh]; r.w = A4[hh].w * fw[hh];
            *(float4*)&Amrg[w - 1][hh * D + 4 * l] = r;
        }
    }
    __syncthreads();
    if (w == 0) {
        #pragma unroll
        for (int hh = 0; hh < H; ++hh) {
            float inv = 1.f / zst[hh];
            int o = hh * D + 4 * l;
            float4 r;
            r.x = (A4[hh].x * fw[hh] + Amrg[0][o + 0] + Amrg[1][o + 0] + Amrg[2][o + 0]) * inv;
            r.y = (A4[hh].y * fw[hh] + Amrg[0][o + 1] + Amrg[1][o + 1] + Amrg[2][o + 1]) * inv;
            r.z = (A4[hh].z * fw[hh] + Amrg[0][o + 2] + Amrg[1][o + 2] + Amrg[2][o + 2]) * inv;
            r.w = (A4[hh].w * fw[hh] + Amrg[0][o + 3] + Amrg[1][o + 3] + Amrg[2][o + 3]) * inv;
            *(float4*)&App[(size_t)b * CDIM + o] = r;
        }
    }
}

// ------------------------------------------------ transpose A'' -> A_T[c][b]
__global__ __launch_bounds__(256) void k_T(const float* __restrict__ App,
                                           float* __restrict__ AT) {
    __shared__ float tile[64][65];
    int cb = blockIdx.x;   // 36
    int bb = blockIdx.y;   // 16
    int t = threadIdx.x;
    int tx = t & 63, ty = t >> 6;
    #pragma unroll
    for (int i = 0; i < 64; i += 4)
        tile[ty + i][tx] = App[(size_t)(bb * 64 + ty + i) * CDIM + cb * 64 + tx];
    __syncthreads();
    #pragma unroll
    for (int i = 0; i < 64; i += 4)
        AT[(size_t)(cb * 64 + ty + i) * BGRAPH + bb * 64 + tx] = tile[tx][ty + i];
}

// -------------------------------------- M[c][d]: Wv x Wout contraction + Wres
__global__ __launch_bounds__(256) void k_M(const float* __restrict__ Wv,
                                           const float* __restrict__ Wout,
                                           const float* __restrict__ Wres,
                                           float* __restrict__ M) {
    int c = blockIdx.x;
    int d = threadIdx.x;
    if (c < 2048) {
        int hh = c >> 8, j = c & 255;
        float acc = 0.f;
        #pragma unroll
        for (int r = 0; r < 32; ++r)
            acc += Wv[(size_t)(hh * 32 + r) * D + j] * Wout[(size_t)d * D + hh * 32 + r];
        M[(size_t)c * D + d] = acc;
    } else {
        int j = c - 2048;
        M[(size_t)c * D + d] = Wres[(size_t)d * D + j];
    }
}

// ---------------------- out partials: split-K weighted sum of M rows by A_T
__global__ __launch_bounds__(256) void k_out(const float* __restrict__ AT,
                                             const float* __restrict__ Mm,
                                             float* __restrict__ part) {
    // grid 512: [dchunk(4)][btile(16)][slice(8)]
    int id = blockIdx.x;
    int dchunk = id & 3;
    int btile = (id >> 2) & 15;
    int slice = id >> 6;
    int t = threadIdx.x;
    int lane = t & 63, w = t >> 6;
    int d = dchunk * 64 + lane;
    int b0 = __builtin_amdgcn_readfirstlane(btile * 64 + w * 16);
    int c0 = slice * 288;
    float acc[16];
    #pragma unroll
    for (int i = 0; i < 16; ++i) acc[i] = 0.f;
    for (int c = c0; c < c0 + 288; ++c) {
        float mv = Mm[(size_t)c * D + d];               // coalesced vector load
        const float* ar = AT + (size_t)c * BGRAPH + b0; // wave-uniform -> s_load
        #pragma unroll
        for (int i = 0; i < 16; ++i) acc[i] = fmaf(ar[i], mv, acc[i]);
    }
    #pragma unroll
    for (int i = 0; i < 16; ++i)
        part[((size_t)slice * BGRAPH + b0 + i) * D + d] = acc[i];
}

// ------------------------------------------------------------- final reduce
__global__ __launch_bounds__(256) void k_red(const float* __restrict__ part,
                                             float* __restrict__ out) {
    int i = blockIdx.x * blockDim.x + threadIdx.x;  // over 65536 float4s
    const float4* p4 = (const float4*)part;
    float4 a = p4[i];
    #pragma unroll
    for (int s = 1; s < 8; ++s) {
        float4 v = p4[(size_t)s * 65536 + i];
        a.x += v.x; a.y += v.y; a.z += v.z; a.w += v.w;
    }
    ((float4*)out)[i] = a;
}

// ---------------------------------------------------------------------------
extern "C" void kernel_launch(void* const* d_in, const int* in_sizes, int n_in,
                              void* d_out, int out_size, void* d_ws, size_t ws_size,
                              hipStream_t stream) {
    const float* h = (const float*)d_in[0];
    const int* batch = (const int*)d_in[1];
    const int* cdr = (const int*)d_in[2];
    const int* ifc = (const int*)d_in[3];
    const float* lnkv_w = (const float*)d_in[4];
    const float* lnkv_b = (const float*)d_in[5];
    const float* lnq_w = (const float*)d_in[6];
    const float* lnq_b = (const float*)d_in[7];
    const float* Wk = (const float*)d_in[8];
    const float* Wv = (const float*)d_in[9];
    const float* Wq = (const float*)d_in[10];
    const float* Wres = (const float*)d_in[11];
    const float* Wout = (const float*)d_in[12];
    const float* cdr_bias = (const float*)d_in[13];
    const float* iface_bias = (const float*)d_in[14];
    const float* logit_scale = (const float*)d_in[15];
    int N = in_sizes[0] / D;

    char* ws = (char*)d_ws;
    size_t o = 0;
    int* offs = (int*)(ws + o);            o += 8192;
    float* Wkq_g = (float*)(ws + o);       o += (size_t)BGRAPH * 2048 * 4;   // 8 MB
    float* App = (float*)(ws + o);         o += (size_t)BGRAPH * CDIM * 4;   // 9.44 MB
    float* AT = (float*)(ws + o);          o += (size_t)CDIM * BGRAPH * 4;   // 9.44 MB
    float* Mm = (float*)(ws + o);          o += (size_t)CDIM * D * 4;        // 2.36 MB
    float* part = (float*)(ws + o);        o += (size_t)8 * BGRAPH * D * 4;  // 8 MB

    hipLaunchKernelGGL(k_offsets, dim3((N + 255) / 256), dim3(256), 0, stream,
                       batch, offs, N);
    hipLaunchKernelGGL(k_pool, dim3(BGRAPH), dim3(256), 0, stream,
                       (const float4*)h, offs, Wq, lnq_w, lnq_b, Wk, logit_scale,
                       Wkq_g, App);
    hipLaunchKernelGGL(k_attn, dim3(BGRAPH), dim3(256), 0, stream,
                       (const float4*)h, offs, lnkv_w, lnkv_b, cdr, ifc,
                       cdr_bias, iface_bias, Wkq_g, App);
    hipLaunchKernelGGL(k_T, dim3(36, 16), dim3(256), 0, stream, App, AT);
    hipLaunchKernelGGL(k_M, dim3(CDIM), dim3(256), 0, stream, Wv, Wout, Wres, Mm);
    hipLaunchKernelGGL(k_out, dim3(512), dim3(256), 0, stream, AT, Mm, part);
    hipLaunchKernelGGL(k_red, dim3(256), dim3(256), 0, stream, part, (float*)d_out);
}

// Round 3
// 662.685 us; speedup vs baseline: 1.3820x; 1.3820x over previous
//
#include <hip/hip_runtime.h>
#include <math.h>

#define D 256
#define BGRAPH 1024
#define H 8
#define NW 4
#define CDIM 2304   // 2048 attn cols + 256 mean-residual cols

static constexpr float EPS = 1e-5f;
static constexpr float MEAN_RES_SCALE = 0.2f;
static constexpr float INV_SQRT_HD = 0.17677669529663687f; // 1/sqrt(32)
static constexpr float DEFER_THR = 8.0f;

// ---------------------------------------------------------------- offsets
__global__ void k_offsets(const int* __restrict__ batch, int* __restrict__ offs, int N) {
    int n = blockIdx.x * blockDim.x + threadIdx.x;
    if (n >= N) return;
    int bn = batch[n];
    if (bn < 0) bn = 0;
    if (bn >= BGRAPH) bn = BGRAPH - 1;
    if (n == 0) {
        offs[BGRAPH] = N;
        for (int bb = 0; bb <= bn; ++bb) offs[bb] = 0;
    } else {
        int bp = batch[n - 1];
        if (bp < 0) bp = 0;
        if (bp >= BGRAPH) bp = BGRAPH - 1;
        if (bp != bn)
            for (int bb = bp + 1; bb <= bn; ++bb) offs[bb] = n;
    }
    if (n == N - 1)
        for (int bb = bn + 1; bb < BGRAPH; ++bb) offs[bb] = N;
}

// ------------------------------------- pool (mean/max) + q LN + Wkq, fused
__global__ __launch_bounds__(256) void k_pool(
    const float4* __restrict__ h4, const int* __restrict__ offs,
    const float* __restrict__ Wq, const float* __restrict__ lnq_w,
    const float* __restrict__ lnq_b, const float* __restrict__ Wk,
    const float* __restrict__ logit_scale,
    float* __restrict__ Wkq_g, float* __restrict__ App) {
    __shared__ alignas(16) float psum[NW][D];
    __shared__ alignas(16) float pmax[NW][D];
    __shared__ alignas(16) float cat_s[2 * D];
    __shared__ alignas(16) float q_s[D];
    __shared__ float red_s[2 * NW];

    int b = blockIdx.x;
    int t = threadIdx.x;
    int l = t & 63, w = t >> 6;
    int s = offs[b], e = offs[b + 1];
    int cnt = e - s;

    float4 sum4 = {0.f, 0.f, 0.f, 0.f};
    float4 max4 = {-INFINITY, -INFINITY, -INFINITY, -INFINITY};
    int n = s + w;
    for (; n + NW < e; n += 2 * NW) {          // 2 nodes in flight per wave
        float4 x0 = h4[(size_t)n * 64 + l];
        float4 x1 = h4[(size_t)(n + NW) * 64 + l];
        sum4.x += x0.x + x1.x; sum4.y += x0.y + x1.y;
        sum4.z += x0.z + x1.z; sum4.w += x0.w + x1.w;
        max4.x = fmaxf(max4.x, fmaxf(x0.x, x1.x));
        max4.y = fmaxf(max4.y, fmaxf(x0.y, x1.y));
        max4.z = fmaxf(max4.z, fmaxf(x0.z, x1.z));
        max4.w = fmaxf(max4.w, fmaxf(x0.w, x1.w));
    }
    if (n < e) {
        float4 x0 = h4[(size_t)n * 64 + l];
        sum4.x += x0.x; sum4.y += x0.y; sum4.z += x0.z; sum4.w += x0.w;
        max4.x = fmaxf(max4.x, x0.x); max4.y = fmaxf(max4.y, x0.y);
        max4.z = fmaxf(max4.z, x0.z); max4.w = fmaxf(max4.w, x0.w);
    }
    *(float4*)&psum[w][4 * l] = sum4;
    *(float4*)&pmax[w][4 * l] = max4;
    __syncthreads();

    int d = t;
    float ssum = psum[0][d] + psum[1][d] + psum[2][d] + psum[3][d];
    float smax = fmaxf(fmaxf(pmax[0][d], pmax[1][d]), fmaxf(pmax[2][d], pmax[3][d]));
    float mean = ssum / (cnt > 0 ? (float)cnt : 1.f);
    if (cnt == 0) { mean = 0.f; smax = 0.f; }
    cat_s[d] = mean;
    cat_s[D + d] = smax;
    App[(size_t)b * CDIM + 2048 + d] = MEAN_RES_SCALE * mean;
    __syncthreads();

    // q_pre[d] = cat . Wq[d, :]
    float qp = 0.f;
    const float4* wq4 = (const float4*)(Wq + (size_t)d * 2 * D);
    #pragma unroll 4
    for (int jj = 0; jj < 128; ++jj) {
        float4 wv = wq4[jj];
        float4 cv = *(const float4*)&cat_s[4 * jj];
        qp += wv.x * cv.x + wv.y * cv.y + wv.z * cv.z + wv.w * cv.w;
    }
    // LayerNorm over the 256 q_pre values (one per thread)
    float v1 = qp, v2 = qp * qp;
    #pragma unroll
    for (int dd = 1; dd < 64; dd <<= 1) {
        v1 += __shfl_xor(v1, dd);
        v2 += __shfl_xor(v2, dd);
    }
    if (l == 0) { red_s[w] = v1; red_s[NW + w] = v2; }
    __syncthreads();
    float S1 = red_s[0] + red_s[1] + red_s[2] + red_s[3];
    float S2 = red_s[4] + red_s[5] + red_s[6] + red_s[7];
    float mu = S1 * (1.f / D);
    float var = S2 * (1.f / D) - mu * mu;
    float rstd = rsqrtf(var + EPS);
    q_s[d] = (qp - mu) * rstd * lnq_w[d] + lnq_b[d];
    __syncthreads();

    // Wkq[b,hh,j] = scale * sum_r q[hh*32+r] * Wk[hh*32+r, j]   (j = t)
    float scale = logit_scale[0] * INV_SQRT_HD;
    int j = t;
    #pragma unroll
    for (int hh = 0; hh < H; ++hh) {
        float acc = 0.f;
        #pragma unroll 8
        for (int r = 0; r < 32; ++r)
            acc += q_s[hh * 32 + r] * Wk[(size_t)(hh * 32 + r) * D + j];
        Wkq_g[(size_t)b * 2048 + hh * D + j] = acc * scale;
    }
}

// split-channel reduction: 8 values/lane -> lane ends with full wave-sum of
// channel (l&7), replicated 8x across the wave. 10 shuffles total.
__device__ __forceinline__ float reduce8(float v[8], int l) {
    {
        bool hi = (l & 1) != 0;
        #pragma unroll
        for (int c = 0; c < 4; ++c) {
            float send = hi ? v[2 * c] : v[2 * c + 1];
            float keep = hi ? v[2 * c + 1] : v[2 * c];
            v[c] = keep + __shfl_xor(send, 1);
        }
    }
    {
        bool hi = (l & 2) != 0;
        #pragma unroll
        for (int c = 0; c < 2; ++c) {
            float send = hi ? v[2 * c] : v[2 * c + 1];
            float keep = hi ? v[2 * c + 1] : v[2 * c];
            v[c] = keep + __shfl_xor(send, 2);
        }
    }
    {
        bool hi = (l & 4) != 0;
        float send = hi ? v[0] : v[1];
        float keep = hi ? v[1] : v[0];
        v[0] = keep + __shfl_xor(send, 4);
    }
    v[0] += __shfl_xor(v[0], 8);
    v[0] += __shfl_xor(v[0], 16);
    v[0] += __shfl_xor(v[0], 32);
    return v[0];
}

// 2-channel split reduce: even lanes end with sum(a), odd lanes sum(b). 6 shuffles.
__device__ __forceinline__ float reduce2(float a, float b, int l) {
    bool hi = (l & 1) != 0;
    float send = hi ? a : b;
    float keep = hi ? b : a;
    float r = keep + __shfl_xor(send, 1);
    r += __shfl_xor(r, 2);
    r += __shfl_xor(r, 4);
    r += __shfl_xor(r, 8);
    r += __shfl_xor(r, 16);
    r += __shfl_xor(r, 32);
    return r;
}

// --------------------------- per-graph LN + logits + online softmax + A acc
__global__ __launch_bounds__(256, 4) void k_attn(
    const float4* __restrict__ h4, const int* __restrict__ offs,
    const float* __restrict__ lnkv_w, const float* __restrict__ lnkv_b,
    const int* __restrict__ cdr_mask, const int* __restrict__ iface_mask,
    const float* __restrict__ cdr_bias, const float* __restrict__ iface_bias,
    const float* __restrict__ Wkq_g, float* __restrict__ App) {
    __shared__ union alignas(16) {
        float wkq[H * D];            // used before main loop
        float amrg[NW - 1][H * D];   // used after main loop (post-barrier)
    } u;
    __shared__ alignas(16) float evb[NW][8];
    __shared__ alignas(16) float scb[NW][8];
    __shared__ float mz_s[NW][H];
    __shared__ float zz_s[NW][H];

    int b = blockIdx.x;
    int t = threadIdx.x;
    int l = t & 63, w = t >> 6;
    for (int i = t; i < H * D; i += 256) u.wkq[i] = Wkq_g[(size_t)b * 2048 + i];
    int s = offs[b], e = offs[b + 1];
    float cb = cdr_bias[0], ib = iface_bias[0];
    float4 w4 = *(const float4*)&lnkv_w[4 * l];
    float4 b4 = *(const float4*)&lnkv_b[4 * l];
    __syncthreads();

    if (s == e) {
        for (int i = t; i < H * D; i += 256) App[(size_t)b * CDIM + i] = 0.f;
        return;
    }

    // per-lane fragments: wwkq = lnkv_w * wkq; c1 = sum(w*wkq), c0 = sum(b*wkq)
    float4 wwkq[H];
    float c1p[H], c0p[H];
    #pragma unroll
    for (int hh = 0; hh < H; ++hh) {
        float4 kq = *(const float4*)&u.wkq[hh * D + 4 * l];
        wwkq[hh].x = w4.x * kq.x; wwkq[hh].y = w4.y * kq.y;
        wwkq[hh].z = w4.z * kq.z; wwkq[hh].w = w4.w * kq.w;
        c1p[hh] = wwkq[hh].x + wwkq[hh].y + wwkq[hh].z + wwkq[hh].w;
        c0p[hh] = b4.x * kq.x + b4.y * kq.y + b4.z * kq.z + b4.w * kq.w;
    }
    float myc1 = reduce8(c1p, l);   // c1 for head (l&7)
    float myc0 = reduce8(c0p, l);   // c0 for head (l&7)

    float mref = -INFINITY, z = 0.f;
    float4 A4[H];
    #pragma unroll
    for (int hh = 0; hh < H; ++hh) A4[hh] = {0.f, 0.f, 0.f, 0.f};

    int n = s + w;
    float4 x = {0.f, 0.f, 0.f, 0.f};
    float bias = 0.f;
    if (n < e) {
        x = h4[(size_t)n * 64 + l];
        bias = cb * (float)cdr_mask[n] + ib * (float)iface_mask[n];
    }
    for (; n < e; n += NW) {
        // prefetch next node before the dependent chain
        int n2 = n + NW;
        float4 xn = {0.f, 0.f, 0.f, 0.f};
        float biasn = 0.f;
        if (n2 < e) {
            xn = h4[(size_t)n2 * 64 + l];
            biasn = cb * (float)cdr_mask[n2] + ib * (float)iface_mask[n2];
        }

        // partial head dots on RAW x (LN folded algebraically) + s1/s2
        float v[8];
        #pragma unroll
        for (int hh = 0; hh < H; ++hh)
            v[hh] = x.x * wwkq[hh].x + x.y * wwkq[hh].y +
                    x.z * wwkq[hh].z + x.w * wwkq[hh].w;
        float s1p = x.x + x.y + x.z + x.w;
        float s2p = x.x * x.x + x.y * x.y + x.z * x.z + x.w * x.w;
        float r = reduce8(v, l);            // head (l&7) dot, wave-wide
        float rs = reduce2(s1p, s2p, l);    // even: s1, odd: s2
        float s1 = __shfl(rs, l & ~1);
        float s2 = __shfl(rs, l | 1);
        float mu = s1 * (1.f / D);
        float var = s2 * (1.f / D) - mu * mu;
        float a = rsqrtf(var + EPS);
        float lg = fmaf(r - mu * myc1, a, myc0) + bias;   // logit, head (l&7)

        unsigned long long need = __ballot(lg > mref + DEFER_THR);
        if (need) {                          // rare: reference-max update
            float nm = fmaxf(mref, lg);
            float sc = __expf(mref - nm);    // first hit: exp(-inf)=0
            if (l < 8) scb[w][l] = sc;
            mref = nm;
            z *= sc;
            float4 sa = *(float4*)&scb[w][0];
            float4 sb = *(float4*)&scb[w][4];
            A4[0].x *= sa.x; A4[0].y *= sa.x; A4[0].z *= sa.x; A4[0].w *= sa.x;
            A4[1].x *= sa.y; A4[1].y *= sa.y; A4[1].z *= sa.y; A4[1].w *= sa.y;
            A4[2].x *= sa.z; A4[2].y *= sa.z; A4[2].z *= sa.z; A4[2].w *= sa.z;
            A4[3].x *= sa.w; A4[3].y *= sa.w; A4[3].z *= sa.w; A4[3].w *= sa.w;
            A4[4].x *= sb.x; A4[4].y *= sb.x; A4[4].z *= sb.x; A4[4].w *= sb.x;
            A4[5].x *= sb.y; A4[5].y *= sb.y; A4[5].z *= sb.y; A4[5].w *= sb.y;
            A4[6].x *= sb.z; A4[6].y *= sb.z; A4[6].z *= sb.z; A4[6].w *= sb.z;
            A4[7].x *= sb.w; A4[7].y *= sb.w; A4[7].z *= sb.w; A4[7].w *= sb.w;
        }
        float ev = __expf(lg - mref);        // bounded by e^THR
        if (l < 8) evb[w][l] = ev;
        z += ev;
        float4 ea = *(float4*)&evb[w][0];
        float4 eb = *(float4*)&evb[w][4];
        float cc = -mu * a;
        float4 hl;
        hl.x = fmaf(fmaf(x.x, a, cc), w4.x, b4.x);
        hl.y = fmaf(fmaf(x.y, a, cc), w4.y, b4.y);
        hl.z = fmaf(fmaf(x.z, a, cc), w4.z, b4.z);
        hl.w = fmaf(fmaf(x.w, a, cc), w4.w, b4.w);
        A4[0].x = fmaf(ea.x, hl.x, A4[0].x); A4[0].y = fmaf(ea.x, hl.y, A4[0].y);
        A4[0].z = fmaf(ea.x, hl.z, A4[0].z); A4[0].w = fmaf(ea.x, hl.w, A4[0].w);
        A4[1].x = fmaf(ea.y, hl.x, A4[1].x); A4[1].y = fmaf(ea.y, hl.y, A4[1].y);
        A4[1].z = fmaf(ea.y, hl.z, A4[1].z); A4[1].w = fmaf(ea.y, hl.w, A4[1].w);
        A4[2].x = fmaf(ea.z, hl.x, A4[2].x); A4[2].y = fmaf(ea.z, hl.y, A4[2].y);
        A4[2].z = fmaf(ea.z, hl.z, A4[2].z); A4[2].w = fmaf(ea.z, hl.w, A4[2].w);
        A4[3].x = fmaf(ea.w, hl.x, A4[3].x); A4[3].y = fmaf(ea.w, hl.y, A4[3].y);
        A4[3].z = fmaf(ea.w, hl.z, A4[3].z); A4[3].w = fmaf(ea.w, hl.w, A4[3].w);
        A4[4].x = fmaf(eb.x, hl.x, A4[4].x); A4[4].y = fmaf(eb.x, hl.y, A4[4].y);
        A4[4].z = fmaf(eb.x, hl.z, A4[4].z); A4[4].w = fmaf(eb.x, hl.w, A4[4].w);
        A4[5].x = fmaf(eb.y, hl.x, A4[5].x); A4[5].y = fmaf(eb.y, hl.y, A4[5].y);
        A4[5].z = fmaf(eb.y, hl.z, A4[5].z); A4[5].w = fmaf(eb.y, hl.w, A4[5].w);
        A4[6].x = fmaf(eb.z, hl.x, A4[6].x); A4[6].y = fmaf(eb.z, hl.y, A4[6].y);
        A4[6].z = fmaf(eb.z, hl.z, A4[6].z); A4[6].w = fmaf(eb.z, hl.w, A4[6].w);
        A4[7].x = fmaf(eb.w, hl.x, A4[7].x); A4[7].y = fmaf(eb.w, hl.y, A4[7].y);
        A4[7].z = fmaf(eb.w, hl.z, A4[7].z); A4[7].w = fmaf(eb.w, hl.w, A4[7].w);

        x = xn; bias = biasn;
    }

    // merge 4 waves (z/mref live in lanes l<8, replicated)
    if (l < 8) { mz_s[w][l] = mref; zz_s[w][l] = z; }
    __syncthreads();
    float fw[H], zst[H];
    #pragma unroll
    for (int hh = 0; hh < H; ++hh) {
        float ms = fmaxf(fmaxf(mz_s[0][hh], mz_s[1][hh]), fmaxf(mz_s[2][hh], mz_s[3][hh]));
        float zs = 0.f;
        #pragma unroll
        for (int ww = 0; ww < NW; ++ww) zs += zz_s[ww][hh] * __expf(mz_s[ww][hh] - ms);
        zst[hh] = zs;
        fw[hh] = __expf(mz_s[w][hh] - ms);
    }
    if (w > 0) {
        #pragma unroll
        for (int hh = 0; hh < H; ++hh) {
            float4 r;
            r.x = A4[hh].x * fw[hh]; r.y = A4[hh].y * fw[hh];
            r.z = A4[hh].z * fw[hh]; r.w = A4[hh].w * fw[hh];
            *(float4*)&u.amrg[w - 1][hh * D + 4 * l] = r;
        }
    }
    __syncthreads();
    if (w == 0) {
        #pragma unroll
        for (int hh = 0; hh < H; ++hh) {
            float inv = 1.f / zst[hh];
            int o = hh * D + 4 * l;
            float4 r;
            r.x = (A4[hh].x * fw[hh] + u.amrg[0][o + 0] + u.amrg[1][o + 0] + u.amrg[2][o + 0]) * inv;
            r.y = (A4[hh].y * fw[hh] + u.amrg[0][o + 1] + u.amrg[1][o + 1] + u.amrg[2][o + 1]) * inv;
            r.z = (A4[hh].z * fw[hh] + u.amrg[0][o + 2] + u.amrg[1][o + 2] + u.amrg[2][o + 2]) * inv;
            r.w = (A4[hh].w * fw[hh] + u.amrg[0][o + 3] + u.amrg[1][o + 3] + u.amrg[2][o + 3]) * inv;
            *(float4*)&App[(size_t)b * CDIM + o] = r;
        }
    }
}

// ------------------------------------------------ transpose A'' -> A_T[c][b]
__global__ __launch_bounds__(256) void k_T(const float* __restrict__ App,
                                           float* __restrict__ AT) {
    __shared__ float tile[64][65];
    int cb = blockIdx.x;   // 36
    int bb = blockIdx.y;   // 16
    int t = threadIdx.x;
    int tx = t & 63, ty = t >> 6;
    #pragma unroll
    for (int i = 0; i < 64; i += 4)
        tile[ty + i][tx] = App[(size_t)(bb * 64 + ty + i) * CDIM + cb * 64 + tx];
    __syncthreads();
    #pragma unroll
    for (int i = 0; i < 64; i += 4)
        AT[(size_t)(cb * 64 + ty + i) * BGRAPH + bb * 64 + tx] = tile[tx][ty + i];
}

// -------------------------------------- M[c][d]: Wv x Wout contraction + Wres
__global__ __launch_bounds__(256) void k_M(const float* __restrict__ Wv,
                                           const float* __restrict__ Wout,
                                           const float* __restrict__ Wres,
                                           float* __restrict__ M) {
    int c = blockIdx.x;
    int d = threadIdx.x;
    if (c < 2048) {
        int hh = c >> 8, j = c & 255;
        float acc = 0.f;
        #pragma unroll
        for (int r = 0; r < 32; ++r)
            acc += Wv[(size_t)(hh * 32 + r) * D + j] * Wout[(size_t)d * D + hh * 32 + r];
        M[(size_t)c * D + d] = acc;
    } else {
        int j = c - 2048;
        M[(size_t)c * D + d] = Wres[(size_t)d * D + j];
    }
}

// ---------------------- out partials: split-K weighted sum of M rows by A_T
__global__ __launch_bounds__(256) void k_out(const float* __restrict__ AT,
                                             const float* __restrict__ Mm,
                                             float* __restrict__ part) {
    // grid 512: [dchunk(4)][btile(16)][slice(8)]
    int id = blockIdx.x;
    int dchunk = id & 3;
    int btile = (id >> 2) & 15;
    int slice = id >> 6;
    int t = threadIdx.x;
    int lane = t & 63, w = t >> 6;
    int d = dchunk * 64 + lane;
    int b0 = __builtin_amdgcn_readfirstlane(btile * 64 + w * 16);
    int c0 = slice * 288;
    float acc[16];
    #pragma unroll
    for (int i = 0; i < 16; ++i) acc[i] = 0.f;
    for (int c = c0; c < c0 + 288; ++c) {
        float mv = Mm[(size_t)c * D + d];               // coalesced vector load
        const float* ar = AT + (size_t)c * BGRAPH + b0; // wave-uniform -> s_load
        #pragma unroll
        for (int i = 0; i < 16; ++i) acc[i] = fmaf(ar[i], mv, acc[i]);
    }
    #pragma unroll
    for (int i = 0; i < 16; ++i)
        part[((size_t)slice * BGRAPH + b0 + i) * D + d] = acc[i];
}

// ------------------------------------------------------------- final reduce
__global__ __launch_bounds__(256) void k_red(const float* __restrict__ part,
                                             float* __restrict__ out) {
    int i = blockIdx.x * blockDim.x + threadIdx.x;  // over 65536 float4s
    const float4* p4 = (const float4*)part;
    float4 a = p4[i];
    #pragma unroll
    for (int s = 1; s < 8; ++s) {
        float4 v = p4[(size_t)s * 65536 + i];
        a.x += v.x; a.y += v.y; a.z += v.z; a.w += v.w;
    }
    ((float4*)out)[i] = a;
}

// ---------------------------------------------------------------------------
extern "C" void kernel_launch(void* const* d_in, const int* in_sizes, int n_in,
                              void* d_out, int out_size, void* d_ws, size_t ws_size,
                              hipStream_t stream) {
    const float* h = (const float*)d_in[0];
    const int* batch = (const int*)d_in[1];
    const int* cdr = (const int*)d_in[2];
    const int* ifc = (const int*)d_in[3];
    const float* lnkv_w = (const float*)d_in[4];
    const float* lnkv_b = (const float*)d_in[5];
    const float* lnq_w = (const float*)d_in[6];
    const float* lnq_b = (const float*)d_in[7];
    const float* Wk = (const float*)d_in[8];
    const float* Wv = (const float*)d_in[9];
    const float* Wq = (const float*)d_in[10];
    const float* Wres = (const float*)d_in[11];
    const float* Wout = (const float*)d_in[12];
    const float* cdr_bias = (const float*)d_in[13];
    const float* iface_bias = (const float*)d_in[14];
    const float* logit_scale = (const float*)d_in[15];
    int N = in_sizes[0] / D;

    char* ws = (char*)d_ws;
    size_t o = 0;
    int* offs = (int*)(ws + o);            o += 8192;
    float* Wkq_g = (float*)(ws + o);       o += (size_t)BGRAPH * 2048 * 4;   // 8 MB
    float* App = (float*)(ws + o);         o += (size_t)BGRAPH * CDIM * 4;   // 9.44 MB
    float* AT = (float*)(ws + o);          o += (size_t)CDIM * BGRAPH * 4;   // 9.44 MB
    float* Mm = (float*)(ws + o);          o += (size_t)CDIM * D * 4;        // 2.36 MB
    float* part = (float*)(ws + o);        o += (size_t)8 * BGRAPH * D * 4;  // 8 MB

    hipLaunchKernelGGL(k_offsets, dim3((N + 255) / 256), dim3(256), 0, stream,
                       batch, offs, N);
    hipLaunchKernelGGL(k_pool, dim3(BGRAPH), dim3(256), 0, stream,
                       (const float4*)h, offs, Wq, lnq_w, lnq_b, Wk, logit_scale,
                       Wkq_g, App);
    hipLaunchKernelGGL(k_attn, dim3(BGRAPH), dim3(256), 0, stream,
                       (const float4*)h, offs, lnkv_w, lnkv_b, cdr, ifc,
                       cdr_bias, iface_bias, Wkq_g, App);
    hipLaunchKernelGGL(k_T, dim3(36, 16), dim3(256), 0, stream, App, AT);
    hipLaunchKernelGGL(k_M, dim3(CDIM), dim3(256), 0, stream, Wv, Wout, Wres, Mm);
    hipLaunchKernelGGL(k_out, dim3(512), dim3(256), 0, stream, AT, Mm, part);
    hipLaunchKernelGGL(k_red, dim3(256), dim3(256), 0, stream, part, (float*)d_out);
}